// Round 9
// baseline (162.884 us; speedup 1.0000x reference)
//
#include <hip/hip_runtime.h>

// FermiLayer fused kernel set for MI355X (gfx950).
// Inputs (f32): h1(768,256) h2(768,768,64) W1n(1216,256) b1n(256)
//               W1e(1216,256) b1e(256) W2(4,64,64) b2(4,64)
// Outputs (f32, concat): h1_out(768,256), h2_out(768,768,64)
//
// Lessons encoded:
//  R6: out2 MUST use nontemporal stores (plain stores evict h2 from L3 in
//      the graph-replay regime; ~30 µs/replay even if rocprof looks better).
//  R7: prefix work must be FUSED into the h2 kernel grid (separate launch
//      serializes ~7 µs).
//  R8: nt stores must be LANE-CONTIGUOUS (1 KB/instr full 128-B lines);
//      scattered nt stores inflate WRITE ~4/3. LDS-linearize the epilogue.
//  R9: pipeline tiles within a block; raw s_barrier + lgkmcnt-only waits
//      (no vmcnt(0) drain); hv loads issued OLDEST so vmcnt FIFO doesn't
//      force prefetch drain.

#define H1OUT_ELEMS (768 * 256)

typedef short short8 __attribute__((ext_vector_type(8)));
typedef float f32x4 __attribute__((ext_vector_type(4)));

__device__ __forceinline__ unsigned short f2bf(float f) {
    unsigned u = __builtin_bit_cast(unsigned, f);
    unsigned r = u + 0x7fffu + ((u >> 16) & 1u);
    return (unsigned short)(r >> 16);
}

// out = (hv + gelu_rescaled(x)) / sqrt(2), tanh-approx gelu.
__device__ __forceinline__ float gelu_res(float x, float hv) {
    float x2 = x * x;
    float z = x * fmaf(-0.1029432196f, x2, -2.3025850930f);
    float e = __builtin_amdgcn_exp2f(z);
    float r = __builtin_amdgcn_rcpf(1.f + e);
    return fmaf(x * r, 1.2111740f, hv * 0.70710678f);
}

#define BARRIER()                                                           \
    asm volatile("s_waitcnt lgkmcnt(0)" ::: "memory");                      \
    __builtin_amdgcn_s_barrier();                                           \
    asm volatile("" ::: "memory")

#define LOADA(AF, CT)                                                       \
    {                                                                       \
        const float* an_ = rowbase + (size_t)(CT) * 4096 +                  \
                           (wm * 32 + lr) * 64 + lk * 8;                    \
        _Pragma("unroll") for (int fm_ = 0; fm_ < 2; ++fm_)                 \
        _Pragma("unroll") for (int kh_ = 0; kh_ < 2; ++kh_) {               \
            const float* pp_ = an_ + fm_ * 1024 + kh_ * 32;                 \
            AF[fm_][kh_][0] = *reinterpret_cast<const float4*>(pp_);        \
            AF[fm_][kh_][1] = *reinterpret_cast<const float4*>(pp_ + 4);    \
        }                                                                   \
    }

#define LOADB(P)                                                            \
    {                                                                       \
        const float* wp_ = W2 + (P) * 4096 + we * 32 + lr;                  \
        _Pragma("unroll") for (int fe_ = 0; fe_ < 2; ++fe_)                 \
        _Pragma("unroll") for (int kh_ = 0; kh_ < 2; ++kh_) {               \
            const float* q_ = wp_ + fe_ * 16 + (kh_ * 32 + lk * 8) * 64;    \
            short8 ob_;                                                     \
            _Pragma("unroll") for (int j_ = 0; j_ < 8; ++j_)                \
                ob_[j_] = (short)f2bf(q_[j_ * 64]);                         \
            bF[fe_][kh_] = ob_;                                             \
        }                                                                   \
        bias4[0] = *reinterpret_cast<const f32x4*>(                         \
            b2 + (P) * 64 + we * 32 + lk * 4);                              \
        bias4[1] = *reinterpret_cast<const f32x4*>(                         \
            b2 + (P) * 64 + we * 32 + 16 + lk * 4);                         \
    }

// One pipelined tile step. AFC = current A regs, AFN = next-tile A regs.
// Swapped MFMA: acc lane holds row m=wm*32+fm*16+lr, cols e=we*32+fe*16+lk*4+j.
#define STEP(CT, AFC, AFN, PF)                                              \
    {                                                                       \
        const float* srcT_ = rowbase + (size_t)(CT) * 4096;                 \
        f32x4 hv_[4];                                                       \
        _Pragma("unroll") for (int i_ = 0; i_ < 4; ++i_)                    \
            hv_[i_] = *reinterpret_cast<const f32x4*>(                      \
                srcT_ + i_ * 1024 + t * 4);                                 \
        __builtin_amdgcn_sched_barrier(0);                                  \
        if (PF) LOADA(AFN, (CT) + 1);                                       \
        __builtin_amdgcn_sched_barrier(0);                                  \
        if (we == 0) {                                                      \
            _Pragma("unroll") for (int kh_ = 0; kh_ < 2; ++kh_) {           \
                float4 s0_, s1_;                                            \
                s0_.x = AFC[0][kh_][0].x + AFC[1][kh_][0].x;                \
                s0_.y = AFC[0][kh_][0].y + AFC[1][kh_][0].y;                \
                s0_.z = AFC[0][kh_][0].z + AFC[1][kh_][0].z;                \
                s0_.w = AFC[0][kh_][0].w + AFC[1][kh_][0].w;                \
                s1_.x = AFC[0][kh_][1].x + AFC[1][kh_][1].x;                \
                s1_.y = AFC[0][kh_][1].y + AFC[1][kh_][1].y;                \
                s1_.z = AFC[0][kh_][1].z + AFC[1][kh_][1].z;                \
                s1_.w = AFC[0][kh_][1].w + AFC[1][kh_][1].w;                \
                *reinterpret_cast<float4*>(                                 \
                    &sm.g.red[wm][lr][kh_ * 32 + lk * 8]) = s0_;            \
                *reinterpret_cast<float4*>(                                 \
                    &sm.g.red[wm][lr][kh_ * 32 + lk * 8 + 4]) = s1_;        \
            }                                                               \
        }                                                                   \
        short8 aF_[2][2];                                                   \
        _Pragma("unroll") for (int fm_ = 0; fm_ < 2; ++fm_)                 \
        _Pragma("unroll") for (int kh_ = 0; kh_ < 2; ++kh_) {               \
            short8 oa_;                                                     \
            oa_[0] = (short)f2bf(AFC[fm_][kh_][0].x);                       \
            oa_[1] = (short)f2bf(AFC[fm_][kh_][0].y);                       \
            oa_[2] = (short)f2bf(AFC[fm_][kh_][0].z);                       \
            oa_[3] = (short)f2bf(AFC[fm_][kh_][0].w);                       \
            oa_[4] = (short)f2bf(AFC[fm_][kh_][1].x);                       \
            oa_[5] = (short)f2bf(AFC[fm_][kh_][1].y);                       \
            oa_[6] = (short)f2bf(AFC[fm_][kh_][1].z);                       \
            oa_[7] = (short)f2bf(AFC[fm_][kh_][1].w);                       \
            aF_[fm_][kh_] = oa_;                                            \
        }                                                                   \
        f32x4 acc_[2][2] = {};                                              \
        _Pragma("unroll") for (int kh_ = 0; kh_ < 2; ++kh_)                 \
        _Pragma("unroll") for (int fm_ = 0; fm_ < 2; ++fm_)                 \
        _Pragma("unroll") for (int fe_ = 0; fe_ < 2; ++fe_)                 \
            acc_[fm_][fe_] = __builtin_amdgcn_mfma_f32_16x16x32_bf16(       \
                bF[fe_][kh_], aF_[fm_][kh_], acc_[fm_][fe_], 0, 0, 0);      \
        _Pragma("unroll") for (int fm_ = 0; fm_ < 2; ++fm_) {               \
            const int m_ = wm * 32 + fm_ * 16 + lr;                         \
            _Pragma("unroll") for (int fe_ = 0; fe_ < 2; ++fe_) {           \
                f32x4 x_;                                                   \
                x_[0] = acc_[fm_][fe_][0] + bias4[fe_][0];                  \
                x_[1] = acc_[fm_][fe_][1] + bias4[fe_][1];                  \
                x_[2] = acc_[fm_][fe_][2] + bias4[fe_][2];                  \
                x_[3] = acc_[fm_][fe_][3] + bias4[fe_][3];                  \
                *reinterpret_cast<f32x4*>(                                  \
                    &sm.g.ot[m_][we * 32 + fe_ * 16 + lk * 4]) = x_;        \
            }                                                               \
        }                                                                   \
        BARRIER();                                                          \
        if (t < 64) {                                                       \
            float s_ = 0.f;                                                 \
            _Pragma("unroll") for (int r_ = 0; r_ < 16; ++r_)               \
                s_ += sm.g.red[0][r_][t] + sm.g.red[1][r_][t];              \
            part2[((size_t)n * 12 + (CT)) * 64 + t] = s_;                   \
        }                                                                   \
        float* dst_ = out2 + (size_t)n * 49152 + (size_t)(CT) * 4096;       \
        _Pragma("unroll") for (int i_ = 0; i_ < 4; ++i_) {                  \
            int flat_ = i_ * 1024 + t * 4;                                  \
            f32x4 x4_ = *reinterpret_cast<const f32x4*>(                    \
                &sm.g.ot[flat_ >> 6][flat_ & 63]);                          \
            f32x4 o_;                                                       \
            o_[0] = gelu_res(x4_[0], hv_[i_][0]);                           \
            o_[1] = gelu_res(x4_[1], hv_[i_][1]);                           \
            o_[2] = gelu_res(x4_[2], hv_[i_][2]);                           \
            o_[3] = gelu_res(x4_[3], hv_[i_][3]);                           \
            __builtin_nontemporal_store(o_,                                 \
                reinterpret_cast<f32x4*>(dst_ + flat_));                    \
        }                                                                   \
        BARRIER();                                                          \
    }

// ---------------------------------------------------------------------------
// Fused kernel 1:
//   blocks [0,12):    h1 per-64-row-tile column sums -> part1
//   blocks [12,316):  W1n/W1e transpose-convert -> WT bf16 (64k x 32e tiles)
//   blocks [316, +1536): h2 update, half-row (6 tiles) per block, pipelined
// ---------------------------------------------------------------------------
__global__ __launch_bounds__(256, 4) void k_h2pre(
    const float* __restrict__ h2, const float* __restrict__ W2,
    const float* __restrict__ b2, const float* __restrict__ h1,
    const float* __restrict__ W1n, const float* __restrict__ W1e,
    float* __restrict__ out2, float* __restrict__ part2,
    float* __restrict__ part1, unsigned short* __restrict__ WT) {
    __shared__ union SM {
        struct {
            float red[2][16][68];   // col-sum scratch        8704 B
            float ot[64][68];       // x = acc+bias staging  17408 B
        } g;
        float tile2[64][33];        // W transpose tile (prefix) 8448 B
    } sm;

    int b = blockIdx.x;
    const int t = threadIdx.x;

    if (b < 12) {  // ---- h1 per-64-row-tile column sums ----
        float s = 0.f;
        #pragma unroll 8
        for (int r = 0; r < 64; ++r) s += h1[(size_t)(b * 64 + r) * 256 + t];
        part1[b * 256 + t] = s;
        return;
    }
    if (b < 316) {  // ---- W transpose-convert, 64(k) x 32(e) tiles ----
        int idx = b - 12;              // 0..303
        int mtx = idx / 152;
        int r2  = idx % 152;
        int k0 = (r2 >> 3) * 64, e0 = (r2 & 7) * 32;
        const float* W = mtx ? W1e : W1n;
        #pragma unroll
        for (int i = 0; i < 8; ++i) {
            int j = i * 256 + t;
            int kr = j >> 5, ec = j & 31;
            sm.tile2[kr][ec] = W[(size_t)(k0 + kr) * 256 + e0 + ec];
        }
        __syncthreads();
        int er = t >> 3, k8 = (t & 7) * 8;
        short8 o;
        #pragma unroll
        for (int j = 0; j < 8; ++j) o[j] = (short)f2bf(sm.tile2[k8 + j][er]);
        *reinterpret_cast<short8*>(
            &WT[((size_t)mtx * 256 + e0 + er) * 1216 + k0 + k8]) = o;
        return;
    }

    // ---- h2 update: half-row per block, 6 tiles pipelined ----
    b -= 316;
    const int n = b >> 1;
    const int half = b & 1;

    const int rs = (n < 128) ? 0 : ((n < 448) ? 1 : 2);
    int pcs0, pcs1, pcs2;   // pair type per col-section for this row section
    if (rs == 0)      { pcs0 = 0; pcs1 = 1; pcs2 = 1; }
    else if (rs == 1) { pcs0 = 1; pcs1 = 2; pcs2 = 3; }
    else              { pcs0 = 1; pcs1 = 3; pcs2 = 2; }

    const float* rowbase = h2 + (size_t)n * 49152;
    const int lane = t & 63;
    const int wv = t >> 6;
    const int wm = wv >> 1, we = wv & 1;
    const int lr = lane & 15, lk = lane >> 4;

    short8 bF[2][2];
    f32x4 bias4[2];
    float4 afA[2][2][2], afB[2][2][2];
    const int ct0 = half * 6;

    LOADA(afA, ct0);
    if (half == 0) {
        // cs per tile: {0,0,1,1,1,1}
        LOADB(pcs0);
        STEP(ct0 + 0, afA, afB, 1);
        STEP(ct0 + 1, afB, afA, 1);
        LOADB(pcs1);
        STEP(ct0 + 2, afA, afB, 1);
        STEP(ct0 + 3, afB, afA, 1);
        STEP(ct0 + 4, afA, afB, 1);
        STEP(ct0 + 5, afB, afA, 0);
    } else {
        // cs per tile: {1,2,2,2,2,2}
        LOADB(pcs1);
        STEP(ct0 + 0, afA, afB, 1);
        LOADB(pcs2);
        STEP(ct0 + 1, afB, afA, 1);
        STEP(ct0 + 2, afA, afB, 1);
        STEP(ct0 + 3, afB, afA, 1);
        STEP(ct0 + 4, afA, afB, 1);
        STEP(ct0 + 5, afB, afA, 0);
    }
}

// ---------------------------------------------------------------------------
// Fused kernel 2: build feats rows (16) in LDS, then GEMM vs WT + epilogue.
// grid (48, 2), block 256 (4 waves; each wave 32 output cols). Swapped MFMA.
// ---------------------------------------------------------------------------
__global__ __launch_bounds__(256) void k_h1f(
    const float* __restrict__ h1, const unsigned short* __restrict__ WT,
    const float* __restrict__ part2, const float* __restrict__ part1,
    const float* __restrict__ b1n, const float* __restrict__ b1e,
    float* __restrict__ out1) {
    __shared__ unsigned short FL[16][1224];

    const int n0 = blockIdx.x * 16;
    const int half = blockIdx.y;
    const int t = threadIdx.x;
    const bool dn = (n0 >= 448);
    const bool nucl = (n0 < 128);

    // phase 1: h1 slice (cols 0..255)
    #pragma unroll
    for (int i = 0; i < 16; ++i) {
        int idx = i * 256 + t;
        int r = idx >> 8, c = idx & 255;
        FL[r][c] = f2bf(h1[(size_t)(n0 + r) * 256 + c]);
    }
    // phase 2: h2_mean (cols 256..447)
    #pragma unroll
    for (int i = 0; i < 12; ++i) {
        int idx = i * 256 + t;
        int r = idx / 192, c = idx % 192;
        int sec = c >> 6, d = c & 63;
        int s2 = (dn && sec >= 1) ? (3 - sec) : sec;
        const float* pr = part2 + (size_t)(n0 + r) * 768;
        float s;
        if (s2 == 0) {
            s = (pr[d] + pr[64 + d]) * (1.f / 128.f);
        } else {
            int q0 = (s2 == 1) ? 2 : 7;
            s = 0.f;
            #pragma unroll
            for (int q = 0; q < 5; ++q) s += pr[(q0 + q) * 64 + d];
            s *= (1.f / 320.f);
        }
        FL[r][256 + c] = f2bf(s);
    }
    // phase 3: h1_mean (cols 448..1215), shared across the 16 rows
    #pragma unroll
    for (int i = 0; i < 3; ++i) {
        int j = i * 256 + t;
        int sec = j >> 8, e2 = j & 255;
        int s2 = (dn && sec >= 1) ? (3 - sec) : sec;
        float s;
        if (s2 == 0) {
            s = (part1[e2] + part1[256 + e2]) * (1.f / 128.f);
        } else {
            int q0 = (s2 == 1) ? 2 : 7;
            s = 0.f;
            #pragma unroll
            for (int q = 0; q < 5; ++q) s += part1[(q0 + q) * 256 + e2];
            s *= (1.f / 320.f);
        }
        unsigned short bv = f2bf(s);
        #pragma unroll
        for (int r = 0; r < 16; ++r) FL[r][448 + j] = bv;
    }
    __syncthreads();

    const int w = t >> 6, lane = t & 63;
    const int lr = lane & 15, lk = lane >> 4;
    const int e0 = half * 128 + w * 32;
    const unsigned short* BT = WT + (nucl ? 0 : (size_t)256 * 1216);
    const unsigned short* br0 = BT + (size_t)(e0 + lr) * 1216 + lk * 8;
    const unsigned short* br1 = br0 + (size_t)16 * 1216;
    const unsigned short* ar = &FL[lr][lk * 8];

    f32x4 acc0 = {}, acc1 = {};
    #pragma unroll 2
    for (int k = 0; k < 1216; k += 32) {
        short8 aF = *reinterpret_cast<const short8*>(ar + k);
        short8 b0 = *reinterpret_cast<const short8*>(br0 + k);
        short8 b1 = *reinterpret_cast<const short8*>(br1 + k);
        acc0 = __builtin_amdgcn_mfma_f32_16x16x32_bf16(b0, aF, acc0, 0, 0, 0);
        acc1 = __builtin_amdgcn_mfma_f32_16x16x32_bf16(b1, aF, acc1, 0, 0, 0);
    }

    const float* bb = nucl ? b1n : b1e;
    const int m = n0 + lr;
    #pragma unroll
    for (int j = 0; j < 2; ++j) {
        const f32x4 a = j ? acc1 : acc0;
        int e = e0 + j * 16 + lk * 4;
        f32x4 bias4 = *reinterpret_cast<const f32x4*>(bb + e);
        f32x4 hv = *reinterpret_cast<const f32x4*>(h1 + (size_t)m * 256 + e);
        f32x4 o;
        o[0] = gelu_res(a[0] + bias4[0], hv[0]);
        o[1] = gelu_res(a[1] + bias4[1], hv[1]);
        o[2] = gelu_res(a[2] + bias4[2], hv[2]);
        o[3] = gelu_res(a[3] + bias4[3], hv[3]);
        *reinterpret_cast<f32x4*>(out1 + (size_t)m * 256 + e) = o;
    }
}

// ---------------------------------------------------------------------------
extern "C" void kernel_launch(void* const* d_in, const int* in_sizes, int n_in,
                              void* d_out, int out_size, void* d_ws, size_t ws_size,
                              hipStream_t stream) {
    const float* h1  = (const float*)d_in[0];
    const float* h2  = (const float*)d_in[1];
    const float* W1n = (const float*)d_in[2];
    const float* b1n = (const float*)d_in[3];
    const float* W1e = (const float*)d_in[4];
    const float* b1e = (const float*)d_in[5];
    const float* W2  = (const float*)d_in[6];
    const float* b2  = (const float*)d_in[7];

    float* out1 = (float*)d_out;             // h1_out: 768*256
    float* out2 = out1 + H1OUT_ELEMS;        // h2_out: 768*768*64

    float* part2 = (float*)d_ws;                                  // 768*12*64 f32
    float* part1 = part2 + 768 * 12 * 64;                         // 12*256 f32
    unsigned short* WT = (unsigned short*)(part1 + 12 * 256);     // 2*256*1216 bf16

    k_h2pre<<<dim3(316 + 1536), 256, 0, stream>>>(
        h2, W2, b2, h1, W1n, W1e, out2, part2, part1, WT);
    k_h1f<<<dim3(48, 2), 256, 0, stream>>>(h1, WT, part2, part1, b1n, b1e, out1);
}

// Round 10
// 78.204 us; speedup vs baseline: 2.0828x; 2.0828x over previous
//
#include <hip/hip_runtime.h>

// FermiLayer fused kernel set for MI355X (gfx950).
// Inputs (f32): h1(768,256) h2(768,768,64) W1n(1216,256) b1n(256)
//               W1e(1216,256) b1e(256) W2(4,64,64) b2(4,64)
// Outputs (f32, concat): h1_out(768,256), h2_out(768,768,64)
//
// Lessons encoded:
//  R6: out2 MUST use nontemporal stores (plain stores evict h2 from L3 in
//      the graph-replay regime; ~30 µs/replay even if rocprof looks better).
//  R7: prefix work must be FUSED into the h2 kernel grid (separate launch
//      serializes ~7 µs).
//  R8: nt stores must be LANE-CONTIGUOUS (1 KB/instr full 128-B lines);
//      scattered nt stores inflate WRITE ~4/3. LDS-linearize the epilogue.
//  R9: do NOT multi-tile pipeline with lgkmcnt-only barriers — in-flight
//      window >1 tile thrashes L1/L3 (FETCH+WRITE doubled). One tile per
//      block, full __syncthreads, is the validated regime.
//  R10: preload the linear hv view BEFORE MFMA (latency hidden under
//      compute); derive col-sums from hv registers (one barrier total).

#define H1OUT_ELEMS (768 * 256)

typedef short short8 __attribute__((ext_vector_type(8)));
typedef float f32x4 __attribute__((ext_vector_type(4)));

__device__ __forceinline__ unsigned short f2bf(float f) {
    unsigned u = __builtin_bit_cast(unsigned, f);
    unsigned r = u + 0x7fffu + ((u >> 16) & 1u);
    return (unsigned short)(r >> 16);
}

// out = (hv + gelu_rescaled(x)) / sqrt(2), tanh-approx gelu.
__device__ __forceinline__ float gelu_res(float x, float hv) {
    float x2 = x * x;
    float z = x * fmaf(-0.1029432196f, x2, -2.3025850930f);
    float e = __builtin_amdgcn_exp2f(z);
    float r = __builtin_amdgcn_rcpf(1.f + e);
    return fmaf(x * r, 1.2111740f, hv * 0.70710678f);
}

// ---------------------------------------------------------------------------
// Fused kernel 1:
//   blocks [0,12):    h1 per-64-row-tile column sums -> part1
//   blocks [12,316):  W1n/W1e transpose-convert -> WT bf16 (64k x 32e tiles)
//   blocks [316, +9216): h2 update (zero-LDS MFMA frags) + col sums,
//                        LDS-linearized full-line nt epilogue, hv preloaded
// ---------------------------------------------------------------------------
__global__ __launch_bounds__(256) void k_h2pre(
    const float* __restrict__ h2, const float* __restrict__ W2,
    const float* __restrict__ b2, const float* __restrict__ h1,
    const float* __restrict__ W1n, const float* __restrict__ W1e,
    float* __restrict__ out2, float* __restrict__ part2,
    float* __restrict__ part1, unsigned short* __restrict__ WT) {
    __shared__ union SM {
        struct {
            float ot[64][68];       // x = acc+bias staging  17408 B
            float red[16][68];      // col-sum partials       4352 B
        } g;
        float tile2[64][33];        // W transpose tile (prefix) 8448 B
    } sm;

    int b = blockIdx.x;
    const int t = threadIdx.x;

    if (b < 12) {  // ---- h1 per-64-row-tile column sums ----
        float s = 0.f;
        #pragma unroll 8
        for (int r = 0; r < 64; ++r) s += h1[(size_t)(b * 64 + r) * 256 + t];
        part1[b * 256 + t] = s;
        return;
    }
    if (b < 316) {  // ---- W transpose-convert, 64(k) x 32(e) tiles ----
        int idx = b - 12;              // 0..303
        int mtx = idx / 152;
        int r2  = idx % 152;
        int k0 = (r2 >> 3) * 64, e0 = (r2 & 7) * 32;
        const float* W = mtx ? W1e : W1n;
        #pragma unroll
        for (int i = 0; i < 8; ++i) {
            int j = i * 256 + t;
            int kr = j >> 5, ec = j & 31;
            sm.tile2[kr][ec] = W[(size_t)(k0 + kr) * 256 + e0 + ec];
        }
        __syncthreads();
        int er = t >> 3, k8 = (t & 7) * 8;
        short8 o;
        #pragma unroll
        for (int j = 0; j < 8; ++j) o[j] = (short)f2bf(sm.tile2[k8 + j][er]);
        *reinterpret_cast<short8*>(
            &WT[((size_t)mtx * 256 + e0 + er) * 1216 + k0 + k8]) = o;
        return;
    }

    // ---- h2 update ----
    b -= 316;
    const int ct = b % 12;
    const int n  = b / 12;
    const int m0 = ct * 64;

    const int rs = (n < 128) ? 0 : ((n < 448) ? 1 : 2);
    const int cs = (ct < 2) ? 0 : ((ct < 7) ? 1 : 2);
    int p;
    if (rs == 0)      p = (cs == 0) ? 0 : 1;
    else if (rs == 1) p = (cs == 0) ? 1 : ((cs == 1) ? 2 : 3);
    else              p = (cs == 0) ? 1 : ((cs == 1) ? 3 : 2);

    const float* src = h2 + ((size_t)n * 768 + m0) * 64;
    const int lane = t & 63;
    const int wv = t >> 6;
    const int wm = wv >> 1, we = wv & 1;
    const int lr = lane & 15, lk = lane >> 4;

    // --- hv preload: linear tile view, 4 x f32x4 per thread (issued FIRST
    //     so HBM/L2 latency hides under frag loads + MFMA) ---
    f32x4 hv[4];
    #pragma unroll
    for (int i = 0; i < 4; ++i)
        hv[i] = *reinterpret_cast<const f32x4*>(src + i * 1024 + t * 4);

    // --- direct A fragment loads (f32, 8 x dwordx4; same lines as hv ->
    //     MSHR/L1 merged, no extra HBM fetch) ---
    const float* arow = src + (wm * 32 + lr) * 64 + lk * 8;
    float4 af[2][2][2];   // [fm][kh][half]
    #pragma unroll
    for (int fm = 0; fm < 2; ++fm)
        #pragma unroll
        for (int kh = 0; kh < 2; ++kh) {
            const float* pp = arow + fm * 1024 + kh * 32;
            af[fm][kh][0] = *reinterpret_cast<const float4*>(pp);
            af[fm][kh][1] = *reinterpret_cast<const float4*>(pp + 4);
        }

    // --- B fragments direct from W2 (scalar f32 columns, L1/L2-hot) ---
    const float* wp = W2 + p * 4096 + we * 32 + lr;
    short8 bF[2][2];   // [fe][kh]
    #pragma unroll
    for (int fe = 0; fe < 2; ++fe)
        #pragma unroll
        for (int kh = 0; kh < 2; ++kh) {
            const float* q = wp + fe * 16 + (kh * 32 + lk * 8) * 64;
            short8 o;
            #pragma unroll
            for (int j = 0; j < 8; ++j) o[j] = (short)f2bf(q[j * 64]);
            bF[fe][kh] = o;
        }

    // --- convert A to bf16 fragments ---
    short8 aF[2][2];
    #pragma unroll
    for (int fm = 0; fm < 2; ++fm)
        #pragma unroll
        for (int kh = 0; kh < 2; ++kh) {
            short8 o;
            o[0] = (short)f2bf(af[fm][kh][0].x);
            o[1] = (short)f2bf(af[fm][kh][0].y);
            o[2] = (short)f2bf(af[fm][kh][0].z);
            o[3] = (short)f2bf(af[fm][kh][0].w);
            o[4] = (short)f2bf(af[fm][kh][1].x);
            o[5] = (short)f2bf(af[fm][kh][1].y);
            o[6] = (short)f2bf(af[fm][kh][1].z);
            o[7] = (short)f2bf(af[fm][kh][1].w);
            aF[fm][kh] = o;
        }

    // --- column partial sums from hv regs: thread sums its 4 rows ---
    {
        f32x4 s;
        s[0] = hv[0][0] + hv[1][0] + hv[2][0] + hv[3][0];
        s[1] = hv[0][1] + hv[1][1] + hv[2][1] + hv[3][1];
        s[2] = hv[0][2] + hv[1][2] + hv[2][2] + hv[3][2];
        s[3] = hv[0][3] + hv[1][3] + hv[2][3] + hv[3][3];
        *reinterpret_cast<f32x4*>(&sm.g.red[t >> 4][(t & 15) * 4]) = s;
    }

    // --- MFMA (R4 orientation): lane holds col e=..+lr, rows m=..+lk*4+r ---
    f32x4 acc[2][2] = {};   // [fm][fe]
    #pragma unroll
    for (int kh = 0; kh < 2; ++kh)
        #pragma unroll
        for (int fm = 0; fm < 2; ++fm)
            #pragma unroll
            for (int fe = 0; fe < 2; ++fe)
                acc[fm][fe] = __builtin_amdgcn_mfma_f32_16x16x32_bf16(
                    aF[fm][kh], bF[fe][kh], acc[fm][fe], 0, 0, 0);

    // --- stage x = acc + bias into LDS (acc layout; 2-way banked = free) ---
    #pragma unroll
    for (int fm = 0; fm < 2; ++fm) {
        #pragma unroll
        for (int fe = 0; fe < 2; ++fe) {
            int e = we * 32 + fe * 16 + lr;
            float bias = b2[p * 64 + e];
            #pragma unroll
            for (int r = 0; r < 4; ++r) {
                int m = wm * 32 + fm * 16 + lk * 4 + r;
                sm.g.ot[m][e] = acc[fm][fe][r] + bias;
            }
        }
    }
    __syncthreads();

    // --- finalize per-tile column sums (concurrent with linear pass) ---
    if (t < 64) {
        float s = 0.f;
        #pragma unroll
        for (int r = 0; r < 16; ++r) s += sm.g.red[r][t];
        part2[((size_t)n * 12 + ct) * 64 + t] = s;
    }

    // --- linear pass: full-line (1 KB/instr) nt stores, hv from regs ---
    float* dst = out2 + ((size_t)n * 768 + m0) * 64;
    #pragma unroll
    for (int i = 0; i < 4; ++i) {
        int flat = i * 1024 + t * 4;
        int m = flat >> 6, e = flat & 63;
        f32x4 x4 = *reinterpret_cast<const f32x4*>(&sm.g.ot[m][e]);
        f32x4 o;
        o[0] = gelu_res(x4[0], hv[i][0]);
        o[1] = gelu_res(x4[1], hv[i][1]);
        o[2] = gelu_res(x4[2], hv[i][2]);
        o[3] = gelu_res(x4[3], hv[i][3]);
        __builtin_nontemporal_store(o, reinterpret_cast<f32x4*>(dst + flat));
    }
}

// ---------------------------------------------------------------------------
// Fused kernel 2: build feats rows (16) in LDS, then GEMM vs WT + epilogue.
// grid (48, 2), block 256 (4 waves; each wave 32 output cols). Swapped MFMA.
// ---------------------------------------------------------------------------
__global__ __launch_bounds__(256) void k_h1f(
    const float* __restrict__ h1, const unsigned short* __restrict__ WT,
    const float* __restrict__ part2, const float* __restrict__ part1,
    const float* __restrict__ b1n, const float* __restrict__ b1e,
    float* __restrict__ out1) {
    __shared__ unsigned short FL[16][1224];

    const int n0 = blockIdx.x * 16;
    const int half = blockIdx.y;
    const int t = threadIdx.x;
    const bool dn = (n0 >= 448);
    const bool nucl = (n0 < 128);

    // phase 1: h1 slice (cols 0..255)
    #pragma unroll
    for (int i = 0; i < 16; ++i) {
        int idx = i * 256 + t;
        int r = idx >> 8, c = idx & 255;
        FL[r][c] = f2bf(h1[(size_t)(n0 + r) * 256 + c]);
    }
    // phase 2: h2_mean (cols 256..447)
    #pragma unroll
    for (int i = 0; i < 12; ++i) {
        int idx = i * 256 + t;
        int r = idx / 192, c = idx % 192;
        int sec = c >> 6, d = c & 63;
        int s2 = (dn && sec >= 1) ? (3 - sec) : sec;
        const float* pr = part2 + (size_t)(n0 + r) * 768;
        float s;
        if (s2 == 0) {
            s = (pr[d] + pr[64 + d]) * (1.f / 128.f);
        } else {
            int q0 = (s2 == 1) ? 2 : 7;
            s = 0.f;
            #pragma unroll
            for (int q = 0; q < 5; ++q) s += pr[(q0 + q) * 64 + d];
            s *= (1.f / 320.f);
        }
        FL[r][256 + c] = f2bf(s);
    }
    // phase 3: h1_mean (cols 448..1215), shared across the 16 rows
    #pragma unroll
    for (int i = 0; i < 3; ++i) {
        int j = i * 256 + t;
        int sec = j >> 8, e2 = j & 255;
        int s2 = (dn && sec >= 1) ? (3 - sec) : sec;
        float s;
        if (s2 == 0) {
            s = (part1[e2] + part1[256 + e2]) * (1.f / 128.f);
        } else {
            int q0 = (s2 == 1) ? 2 : 7;
            s = 0.f;
            #pragma unroll
            for (int q = 0; q < 5; ++q) s += part1[(q0 + q) * 256 + e2];
            s *= (1.f / 320.f);
        }
        unsigned short bv = f2bf(s);
        #pragma unroll
        for (int r = 0; r < 16; ++r) FL[r][448 + j] = bv;
    }
    __syncthreads();

    const int w = t >> 6, lane = t & 63;
    const int lr = lane & 15, lk = lane >> 4;
    const int e0 = half * 128 + w * 32;
    const unsigned short* BT = WT + (nucl ? 0 : (size_t)256 * 1216);
    const unsigned short* br0 = BT + (size_t)(e0 + lr) * 1216 + lk * 8;
    const unsigned short* br1 = br0 + (size_t)16 * 1216;
    const unsigned short* ar = &FL[lr][lk * 8];

    f32x4 acc0 = {}, acc1 = {};
    #pragma unroll 2
    for (int k = 0; k < 1216; k += 32) {
        short8 aF = *reinterpret_cast<const short8*>(ar + k);
        short8 b0 = *reinterpret_cast<const short8*>(br0 + k);
        short8 b1 = *reinterpret_cast<const short8*>(br1 + k);
        acc0 = __builtin_amdgcn_mfma_f32_16x16x32_bf16(b0, aF, acc0, 0, 0, 0);
        acc1 = __builtin_amdgcn_mfma_f32_16x16x32_bf16(b1, aF, acc1, 0, 0, 0);
    }

    const float* bb = nucl ? b1n : b1e;
    const int m = n0 + lr;
    #pragma unroll
    for (int j = 0; j < 2; ++j) {
        const f32x4 a = j ? acc1 : acc0;
        int e = e0 + j * 16 + lk * 4;
        f32x4 bias4 = *reinterpret_cast<const f32x4*>(bb + e);
        f32x4 hv = *reinterpret_cast<const f32x4*>(h1 + (size_t)m * 256 + e);
        f32x4 o;
        o[0] = gelu_res(a[0] + bias4[0], hv[0]);
        o[1] = gelu_res(a[1] + bias4[1], hv[1]);
        o[2] = gelu_res(a[2] + bias4[2], hv[2]);
        o[3] = gelu_res(a[3] + bias4[3], hv[3]);
        *reinterpret_cast<f32x4*>(out1 + (size_t)m * 256 + e) = o;
    }
}

// ---------------------------------------------------------------------------
extern "C" void kernel_launch(void* const* d_in, const int* in_sizes, int n_in,
                              void* d_out, int out_size, void* d_ws, size_t ws_size,
                              hipStream_t stream) {
    const float* h1  = (const float*)d_in[0];
    const float* h2  = (const float*)d_in[1];
    const float* W1n = (const float*)d_in[2];
    const float* b1n = (const float*)d_in[3];
    const float* W1e = (const float*)d_in[4];
    const float* b1e = (const float*)d_in[5];
    const float* W2  = (const float*)d_in[6];
    const float* b2  = (const float*)d_in[7];

    float* out1 = (float*)d_out;             // h1_out: 768*256
    float* out2 = out1 + H1OUT_ELEMS;        // h2_out: 768*768*64

    float* part2 = (float*)d_ws;                                  // 768*12*64 f32
    float* part1 = part2 + 768 * 12 * 64;                         // 12*256 f32
    unsigned short* WT = (unsigned short*)(part1 + 12 * 256);     // 2*256*1216 bf16

    k_h2pre<<<dim3(316 + 12 * 768), 256, 0, stream>>>(
        h2, W2, b2, h1, W1n, W1e, out2, part2, part1, WT);
    k_h1f<<<dim3(48, 2), 256, 0, stream>>>(h1, WT, part2, part1, b1n, b1e, out1);
}

// Round 11
// 73.867 us; speedup vs baseline: 2.2051x; 1.0587x over previous
//
#include <hip/hip_runtime.h>

// FermiLayer fused kernel set for MI355X (gfx950).
// Inputs (f32): h1(768,256) h2(768,768,64) W1n(1216,256) b1n(256)
//               W1e(1216,256) b1e(256) W2(4,64,64) b2(4,64)
// Outputs (f32, concat): h1_out(768,256), h2_out(768,768,64)
//
// Lessons encoded:
//  R6:  out2 MUST use nontemporal stores (plain stores evict h2 from L3 in
//       the graph-replay regime; ~30 µs/replay even if rocprof looks better).
//  R7:  prefix work must be FUSED into the h2 kernel grid.
//  R8:  nt stores must be LANE-CONTIGUOUS (1 KB/instr full 128-B lines);
//       LDS-linearize the epilogue.
//  R9:  do NOT hold >1 tile in flight per block (L1/L3 thrash).
//  R10: preload hv before MFMA; col-sums from hv registers.
//  R11: wave-owns-16-rows decomposition -> x-staging + epilogue are
//       wave-local, no post-MFMA barrier; single EARLY barrier (lgkmcnt
//       only) for the part2 cross-wave reduction.

#define H1OUT_ELEMS (768 * 256)

typedef short short8 __attribute__((ext_vector_type(8)));
typedef float f32x4 __attribute__((ext_vector_type(4)));

__device__ __forceinline__ unsigned short f2bf(float f) {
    unsigned u = __builtin_bit_cast(unsigned, f);
    unsigned r = u + 0x7fffu + ((u >> 16) & 1u);
    return (unsigned short)(r >> 16);
}

// out = (hv + gelu_rescaled(x)) / sqrt(2), tanh-approx gelu.
__device__ __forceinline__ float gelu_res(float x, float hv) {
    float x2 = x * x;
    float z = x * fmaf(-0.1029432196f, x2, -2.3025850930f);
    float e = __builtin_amdgcn_exp2f(z);
    float r = __builtin_amdgcn_rcpf(1.f + e);
    return fmaf(x * r, 1.2111740f, hv * 0.70710678f);
}

// ---------------------------------------------------------------------------
// Fused kernel 1:
//   blocks [0,12):    h1 per-64-row-tile column sums -> part1
//   blocks [12,316):  W1n/W1e transpose-convert -> WT bf16 (64k x 32e tiles)
//   blocks [316, +9216): h2 update; wave-local 16-row bands, one early barrier
// ---------------------------------------------------------------------------
__global__ __launch_bounds__(256) void k_h2pre(
    const float* __restrict__ h2, const float* __restrict__ W2,
    const float* __restrict__ b2, const float* __restrict__ h1,
    const float* __restrict__ W1n, const float* __restrict__ W1e,
    float* __restrict__ out2, float* __restrict__ part2,
    float* __restrict__ part1, unsigned short* __restrict__ WT) {
    __shared__ union SM {
        struct {
            float ot[4][16][68];    // per-wave x staging    17408 B
            float red[4][4][64];    // col-sum partials       4096 B
        } g;
        float tile2[64][33];        // W transpose tile (prefix) 8448 B
    } sm;

    int b = blockIdx.x;
    const int t = threadIdx.x;

    if (b < 12) {  // ---- h1 per-64-row-tile column sums ----
        float s = 0.f;
        #pragma unroll 8
        for (int r = 0; r < 64; ++r) s += h1[(size_t)(b * 64 + r) * 256 + t];
        part1[b * 256 + t] = s;
        return;
    }
    if (b < 316) {  // ---- W transpose-convert, 64(k) x 32(e) tiles ----
        int idx = b - 12;              // 0..303
        int mtx = idx / 152;
        int r2  = idx % 152;
        int k0 = (r2 >> 3) * 64, e0 = (r2 & 7) * 32;
        const float* W = mtx ? W1e : W1n;
        #pragma unroll
        for (int i = 0; i < 8; ++i) {
            int j = i * 256 + t;
            int kr = j >> 5, ec = j & 31;
            sm.tile2[kr][ec] = W[(size_t)(k0 + kr) * 256 + e0 + ec];
        }
        __syncthreads();
        int er = t >> 3, k8 = (t & 7) * 8;
        short8 o;
        #pragma unroll
        for (int j = 0; j < 8; ++j) o[j] = (short)f2bf(sm.tile2[k8 + j][er]);
        *reinterpret_cast<short8*>(
            &WT[((size_t)mtx * 256 + e0 + er) * 1216 + k0 + k8]) = o;
        return;
    }

    // ---- h2 update: each wave owns 16 rows x 64 cols of the 64x64 tile ----
    b -= 316;
    const int ct = b % 12;
    const int n  = b / 12;
    const int m0 = ct * 64;

    const int rs = (n < 128) ? 0 : ((n < 448) ? 1 : 2);
    const int cs = (ct < 2) ? 0 : ((ct < 7) ? 1 : 2);
    int p;
    if (rs == 0)      p = (cs == 0) ? 0 : 1;
    else if (rs == 1) p = (cs == 0) ? 1 : ((cs == 1) ? 2 : 3);
    else              p = (cs == 0) ? 1 : ((cs == 1) ? 3 : 2);

    const float* src = h2 + ((size_t)n * 768 + m0) * 64;
    const int lane = t & 63;
    const int w = t >> 6;          // wave id = 16-row band
    const int lr = lane & 15, lk = lane >> 4;
    const int r0 = w * 16;

    // --- hv: wave-local linear view of rows r0..r0+15 (full-line loads) ---
    const float* hbase = src + r0 * 64;
    f32x4 hv[4];
    #pragma unroll
    for (int i = 0; i < 4; ++i)
        hv[i] = *reinterpret_cast<const f32x4*>(hbase + i * 256 + lane * 4);

    // --- A-frag loads (rows r0+lr), stay in flight across the barrier ---
    const float* arow = src + (r0 + lr) * 64 + lk * 8;
    float4 af[2][2];
    #pragma unroll
    for (int kh = 0; kh < 2; ++kh) {
        af[kh][0] = *reinterpret_cast<const float4*>(arow + kh * 32);
        af[kh][1] = *reinterpret_cast<const float4*>(arow + kh * 32 + 4);
    }

    // --- column partial sums of this wave's 16 rows (from hv regs) ---
    {
        f32x4 s;
        s[0] = hv[0][0] + hv[1][0] + hv[2][0] + hv[3][0];
        s[1] = hv[0][1] + hv[1][1] + hv[2][1] + hv[3][1];
        s[2] = hv[0][2] + hv[1][2] + hv[2][2] + hv[3][2];
        s[3] = hv[0][3] + hv[1][3] + hv[2][3] + hv[3][3];
        *reinterpret_cast<f32x4*>(&sm.g.red[w][lane >> 4][(lane & 15) * 4]) = s;
    }

    // --- the ONLY barrier: lgkmcnt-only (A loads stay in flight) ---
    asm volatile("s_waitcnt lgkmcnt(0)" ::: "memory");
    __builtin_amdgcn_s_barrier();
    asm volatile("" ::: "memory");

    // --- part2 finalize (wave 0 only; others proceed to MFMA) ---
    if (t < 64) {
        float s = 0.f;
        #pragma unroll
        for (int q = 0; q < 16; ++q) s += sm.g.red[q >> 2][q & 3][t];
        part2[((size_t)n * 12 + ct) * 64 + t] = s;
    }

    // --- convert A to bf16 fragments ---
    short8 aF[2];
    #pragma unroll
    for (int kh = 0; kh < 2; ++kh) {
        short8 o;
        o[0] = (short)f2bf(af[kh][0].x);
        o[1] = (short)f2bf(af[kh][0].y);
        o[2] = (short)f2bf(af[kh][0].z);
        o[3] = (short)f2bf(af[kh][0].w);
        o[4] = (short)f2bf(af[kh][1].x);
        o[5] = (short)f2bf(af[kh][1].y);
        o[6] = (short)f2bf(af[kh][1].z);
        o[7] = (short)f2bf(af[kh][1].w);
        aF[kh] = o;
    }

    // --- per 16-col block: B load+cvt (L1-hot), 2 MFMA, stage x (wave-local)
    //     D layout (R4 orientation): lane holds col e=fe*16+lr,
    //     rows m = r0 + lk*4 + r ---
    const float* wp = W2 + p * 4096;
    #pragma unroll
    for (int fe = 0; fe < 4; ++fe) {
        const float* q = wp + fe * 16 + lr;
        short8 b0, b1;
        #pragma unroll
        for (int j = 0; j < 8; ++j) {
            b0[j] = (short)f2bf(q[(lk * 8 + j) * 64]);
            b1[j] = (short)f2bf(q[(32 + lk * 8 + j) * 64]);
        }
        f32x4 acc = {};
        acc = __builtin_amdgcn_mfma_f32_16x16x32_bf16(aF[0], b0, acc, 0, 0, 0);
        acc = __builtin_amdgcn_mfma_f32_16x16x32_bf16(aF[1], b1, acc, 0, 0, 0);
        float bias = b2[p * 64 + fe * 16 + lr];
        #pragma unroll
        for (int r = 0; r < 4; ++r)
            sm.g.ot[w][lk * 4 + r][fe * 16 + lr] = acc[r] + bias;
    }

    // --- wave-local epilogue: LDS transpose-read + gelu + full-line nt store
    //     (compiler inserts lgkmcnt for the same-wave ot dependency) ---
    float* dst = out2 + ((size_t)n * 768 + m0 + r0) * 64;
    #pragma unroll
    for (int i = 0; i < 4; ++i) {
        int row = i * 4 + (lane >> 4), col = (lane & 15) * 4;
        f32x4 x4 = *reinterpret_cast<const f32x4*>(&sm.g.ot[w][row][col]);
        f32x4 o;
        o[0] = gelu_res(x4[0], hv[i][0]);
        o[1] = gelu_res(x4[1], hv[i][1]);
        o[2] = gelu_res(x4[2], hv[i][2]);
        o[3] = gelu_res(x4[3], hv[i][3]);
        __builtin_nontemporal_store(
            o, reinterpret_cast<f32x4*>(dst + i * 256 + lane * 4));
    }
}

// ---------------------------------------------------------------------------
// Fused kernel 2: build feats rows (16) in LDS, then GEMM vs WT + epilogue.
// grid (48, 2), block 256 (4 waves; each wave 32 output cols). Swapped MFMA.
// ---------------------------------------------------------------------------
__global__ __launch_bounds__(256) void k_h1f(
    const float* __restrict__ h1, const unsigned short* __restrict__ WT,
    const float* __restrict__ part2, const float* __restrict__ part1,
    const float* __restrict__ b1n, const float* __restrict__ b1e,
    float* __restrict__ out1) {
    __shared__ unsigned short FL[16][1224];

    const int n0 = blockIdx.x * 16;
    const int half = blockIdx.y;
    const int t = threadIdx.x;
    const bool dn = (n0 >= 448);
    const bool nucl = (n0 < 128);

    // phase 1: h1 slice (cols 0..255)
    #pragma unroll
    for (int i = 0; i < 16; ++i) {
        int idx = i * 256 + t;
        int r = idx >> 8, c = idx & 255;
        FL[r][c] = f2bf(h1[(size_t)(n0 + r) * 256 + c]);
    }
    // phase 2: h2_mean (cols 256..447)
    #pragma unroll
    for (int i = 0; i < 12; ++i) {
        int idx = i * 256 + t;
        int r = idx / 192, c = idx % 192;
        int sec = c >> 6, d = c & 63;
        int s2 = (dn && sec >= 1) ? (3 - sec) : sec;
        const float* pr = part2 + (size_t)(n0 + r) * 768;
        float s;
        if (s2 == 0) {
            s = (pr[d] + pr[64 + d]) * (1.f / 128.f);
        } else {
            int q0 = (s2 == 1) ? 2 : 7;
            s = 0.f;
            #pragma unroll
            for (int q = 0; q < 5; ++q) s += pr[(q0 + q) * 64 + d];
            s *= (1.f / 320.f);
        }
        FL[r][256 + c] = f2bf(s);
    }
    // phase 3: h1_mean (cols 448..1215), shared across the 16 rows
    #pragma unroll
    for (int i = 0; i < 3; ++i) {
        int j = i * 256 + t;
        int sec = j >> 8, e2 = j & 255;
        int s2 = (dn && sec >= 1) ? (3 - sec) : sec;
        float s;
        if (s2 == 0) {
            s = (part1[e2] + part1[256 + e2]) * (1.f / 128.f);
        } else {
            int q0 = (s2 == 1) ? 2 : 7;
            s = 0.f;
            #pragma unroll
            for (int q = 0; q < 5; ++q) s += part1[(q0 + q) * 256 + e2];
            s *= (1.f / 320.f);
        }
        unsigned short bv = f2bf(s);
        #pragma unroll
        for (int r = 0; r < 16; ++r) FL[r][448 + j] = bv;
    }
    __syncthreads();

    const int w = t >> 6, lane = t & 63;
    const int lr = lane & 15, lk = lane >> 4;
    const int e0 = half * 128 + w * 32;
    const unsigned short* BT = WT + (nucl ? 0 : (size_t)256 * 1216);
    const unsigned short* br0 = BT + (size_t)(e0 + lr) * 1216 + lk * 8;
    const unsigned short* br1 = br0 + (size_t)16 * 1216;
    const unsigned short* ar = &FL[lr][lk * 8];

    f32x4 acc0 = {}, acc1 = {};
    #pragma unroll 2
    for (int k = 0; k < 1216; k += 32) {
        short8 aF = *reinterpret_cast<const short8*>(ar + k);
        short8 b0 = *reinterpret_cast<const short8*>(br0 + k);
        short8 b1 = *reinterpret_cast<const short8*>(br1 + k);
        acc0 = __builtin_amdgcn_mfma_f32_16x16x32_bf16(b0, aF, acc0, 0, 0, 0);
        acc1 = __builtin_amdgcn_mfma_f32_16x16x32_bf16(b1, aF, acc1, 0, 0, 0);
    }

    const float* bb = nucl ? b1n : b1e;
    const int m = n0 + lr;
    #pragma unroll
    for (int j = 0; j < 2; ++j) {
        const f32x4 a = j ? acc1 : acc0;
        int e = e0 + j * 16 + lk * 4;
        f32x4 bias4 = *reinterpret_cast<const f32x4*>(bb + e);
        f32x4 hv = *reinterpret_cast<const f32x4*>(h1 + (size_t)m * 256 + e);
        f32x4 o;
        o[0] = gelu_res(a[0] + bias4[0], hv[0]);
        o[1] = gelu_res(a[1] + bias4[1], hv[1]);
        o[2] = gelu_res(a[2] + bias4[2], hv[2]);
        o[3] = gelu_res(a[3] + bias4[3], hv[3]);
        *reinterpret_cast<f32x4*>(out1 + (size_t)m * 256 + e) = o;
    }
}

// ---------------------------------------------------------------------------
extern "C" void kernel_launch(void* const* d_in, const int* in_sizes, int n_in,
                              void* d_out, int out_size, void* d_ws, size_t ws_size,
                              hipStream_t stream) {
    const float* h1  = (const float*)d_in[0];
    const float* h2  = (const float*)d_in[1];
    const float* W1n = (const float*)d_in[2];
    const float* b1n = (const float*)d_in[3];
    const float* W1e = (const float*)d_in[4];
    const float* b1e = (const float*)d_in[5];
    const float* W2  = (const float*)d_in[6];
    const float* b2  = (const float*)d_in[7];

    float* out1 = (float*)d_out;             // h1_out: 768*256
    float* out2 = out1 + H1OUT_ELEMS;        // h2_out: 768*768*64

    float* part2 = (float*)d_ws;                                  // 768*12*64 f32
    float* part1 = part2 + 768 * 12 * 64;                         // 12*256 f32
    unsigned short* WT = (unsigned short*)(part1 + 12 * 256);     // 2*256*1216 bf16

    k_h2pre<<<dim3(316 + 12 * 768), 256, 0, stream>>>(
        h2, W2, b2, h1, W1n, W1e, out2, part2, part1, WT);
    k_h1f<<<dim3(48, 2), 256, 0, stream>>>(h1, WT, part2, part1, b1n, b1e, out1);
}